// Round 2
// baseline (429.246 us; speedup 1.0000x reference)
//
#include <hip/hip_runtime.h>

#define NL 64
#define SQ 512
#define BATCH 1024

// One wave (64 lanes) per batch row; lane j owns label j.
// Recurrence rewritten as: next[j] = emit[t,j] + C + log( sum_i exp(score_i - C) * ET[i][j] )
// with ET = exp(transitions) held in 64 VGPRs per lane (column j), C = readfirstlane(score).
// C is lane-uniform and within ~10s of max(score), so exp stays in range (fp32 overflows at 88).
__global__ __launch_bounds__(64) void crf_fwd(
    const float* __restrict__ emissions,   // [B, S, L]
    const int*   __restrict__ mask,        // [B, S]
    const float* __restrict__ trans,       // [L, L]  (prev, next)
    const float* __restrict__ start_t,     // [L]
    const float* __restrict__ end_t,       // [L]
    float* __restrict__ out)               // [B]
{
    const int b = blockIdx.x;
    const int j = threadIdx.x;             // next-label index

    const float* em = emissions + (size_t)b * SQ * NL;
    const int*   mk = mask + (size_t)b * SQ;

    // ET column j: et[i] = exp(trans[i][j]); loads coalesced across lanes per i.
    float et[NL];
#pragma unroll
    for (int i = 0; i < NL; ++i)
        et[i] = __expf(trans[i * NL + j]);

    __shared__ __align__(16) float e_lds[NL];

    float score = start_t[j] + em[j];      // t = 0

    float emit_next = em[NL + j];          // prefetch t = 1
    for (int t = 1; t < SQ; ++t) {
        const float emit_t = emit_next;
        const int   m_t    = mk[t];        // lane-uniform scalar load
        if (t + 1 < SQ) emit_next = em[(size_t)(t + 1) * NL + j];

        const float C = __shfl(score, 0);  // lane-uniform reference
        const float e = __expf(score - C);
        e_lds[j] = e;
        __syncthreads();

        const float4* e4 = (const float4*)e_lds;
        float s0 = 0.f, s1 = 0.f, s2 = 0.f, s3 = 0.f;
#pragma unroll
        for (int i4 = 0; i4 < NL / 4; i4 += 4) {
            float4 va = e4[i4 + 0];
            float4 vb = e4[i4 + 1];
            float4 vc = e4[i4 + 2];
            float4 vd = e4[i4 + 3];
            s0 += va.x * et[4*i4 + 0]  + va.y * et[4*i4 + 1]
                + va.z * et[4*i4 + 2]  + va.w * et[4*i4 + 3];
            s1 += vb.x * et[4*i4 + 4]  + vb.y * et[4*i4 + 5]
                + vb.z * et[4*i4 + 6]  + vb.w * et[4*i4 + 7];
            s2 += vc.x * et[4*i4 + 8]  + vc.y * et[4*i4 + 9]
                + vc.z * et[4*i4 + 10] + vc.w * et[4*i4 + 11];
            s3 += vd.x * et[4*i4 + 12] + vd.y * et[4*i4 + 13]
                + vd.z * et[4*i4 + 14] + vd.w * et[4*i4 + 15];
        }
        __syncthreads();                   // protect e_lds before next write

        const float sum = (s0 + s1) + (s2 + s3);
        const float ns  = emit_t + C + __logf(sum);
        score = m_t ? ns : score;
    }

    // out[b] = logsumexp_j(score[j] + end_t[j])
    float v = score + end_t[j];
    float m = v;
#pragma unroll
    for (int off = 32; off; off >>= 1) m = fmaxf(m, __shfl_xor(m, off));
    float ex = __expf(v - m);
#pragma unroll
    for (int off = 32; off; off >>= 1) ex += __shfl_xor(ex, off);
    if (j == 0) out[b] = m + __logf(ex);
}

extern "C" void kernel_launch(void* const* d_in, const int* in_sizes, int n_in,
                              void* d_out, int out_size, void* d_ws, size_t ws_size,
                              hipStream_t stream) {
    const float* emissions = (const float*)d_in[0];
    const int*   mask      = (const int*)d_in[1];
    const float* trans     = (const float*)d_in[2];
    const float* start_t   = (const float*)d_in[3];
    const float* end_t     = (const float*)d_in[4];
    float* out = (float*)d_out;

    crf_fwd<<<BATCH, NL, 0, stream>>>(emissions, mask, trans, start_t, end_t, out);
}

// Round 3
// 286.630 us; speedup vs baseline: 1.4976x; 1.4976x over previous
//
#include <hip/hip_runtime.h>

#define NL 64
#define SQ 512
#define BATCH 1024

// Broadcast lane `lane`'s value of v to all lanes via v_readlane (SGPR result).
__device__ __forceinline__ float lane_bcast(float v, int lane) {
    return __uint_as_float(__builtin_amdgcn_readlane(__float_as_uint(v), lane));
}

// One wave per batch row; lane j owns label j.
// Exp-domain recurrence: p_j = exp(score_j - logC) as state.
//   p'_j = expE_j * sum_i p_i * ET[i][j]       (linear step, no log/exp on chain)
// Broadcast of p_i via v_readlane -> SGPR, FMAs read SGPR directly: no LDS,
// no barrier, no shfl on the critical path. Renorm every 4 steps bounds range.
__global__ __launch_bounds__(64) void crf_fwd(
    const float* __restrict__ emissions,   // [B, S, L]
    const int*   __restrict__ mask,        // [B, S]
    const float* __restrict__ trans,       // [L, L]  (prev, next)
    const float* __restrict__ start_t,     // [L]
    const float* __restrict__ end_t,       // [L]
    float* __restrict__ out)               // [B]
{
    const int b = blockIdx.x;
    const int j = threadIdx.x;             // next-label index

    const float* em = emissions + (size_t)b * SQ * NL;
    const int*   mk = mask + (size_t)b * SQ;

    // ET column j: et[i] = exp(trans[i][j]); coalesced across lanes per i.
    float et[NL];
#pragma unroll
    for (int i = 0; i < NL; ++i)
        et[i] = __expf(trans[i * NL + j]);

    // init state from t=0
    float p, logC;
    {
        const float s0 = start_t[j] + em[j];
        const float C  = lane_bcast(s0, 0);
        p    = __expf(s0 - C);
        logC = C;
    }

    // one matvec step (exp domain)
    auto step = [&](float expe, int m) {
        float a0 = 0.f, a1 = 0.f, a2 = 0.f, a3 = 0.f;
#pragma unroll
        for (int i = 0; i < NL; i += 4) {
            const float b0 = lane_bcast(p, i + 0);
            const float b1 = lane_bcast(p, i + 1);
            const float b2 = lane_bcast(p, i + 2);
            const float b3 = lane_bcast(p, i + 3);
            a0 = fmaf(b0, et[i + 0], a0);
            a1 = fmaf(b1, et[i + 1], a1);
            a2 = fmaf(b2, et[i + 2], a2);
            a3 = fmaf(b3, et[i + 3], a3);
        }
        const float pn = expe * ((a0 + a1) + (a2 + a3));
        p = m ? pn : p;
    };

    // software pipeline: raw emissions prefetched one 4-step group ahead
    float raw0 = em[1 * NL + j];
    float raw1 = em[2 * NL + j];
    float raw2 = em[3 * NL + j];
    float raw3 = em[4 * NL + j];

    for (int g = 0; g < 127; ++g) {
        const int t = 1 + 4 * g;           // steps t .. t+3

        const float ex0 = __expf(raw0);
        const float ex1 = __expf(raw1);
        const float ex2 = __expf(raw2);
        const float ex3 = __expf(raw3);

        // prefetch next group (clamp t+7 at 511 for the final group)
        const int t4 = t + 4;
        const int t7 = (t + 7 < SQ) ? (t + 7) : (SQ - 1);
        raw0 = em[t4 * NL + j];
        raw1 = em[(t4 + 1) * NL + j];
        raw2 = em[(t4 + 2) * NL + j];
        raw3 = em[t7 * NL + j];

        const int m0 = mk[t + 0];
        const int m1 = mk[t + 1];
        const int m2 = mk[t + 2];
        const int m3 = mk[t + 3];

        step(ex0, m0);
        step(ex1, m1);
        step(ex2, m2);
        step(ex3, m3);

        // renorm: keep p in fp32 range; score_j = logC + log(p_j) invariant
        const float p0 = lane_bcast(p, 0);
        logC += __logf(p0);
        p *= (1.0f / p0);
    }

    // tail: t = 509, 510, 511 (raws already prefetched; raw3 duplicates 511, unused)
    {
        const float ex0 = __expf(raw0);
        const float ex1 = __expf(raw1);
        const float ex2 = __expf(raw2);
        const int   m0  = mk[509];
        const int   m1  = mk[510];
        const int   m2  = mk[511];
        step(ex0, m0);
        step(ex1, m1);
        step(ex2, m2);
    }

    // out[b] = logC + log( sum_j p_j * exp(end_t[j]) )
    float v = p * __expf(end_t[j]);
#pragma unroll
    for (int off = 32; off; off >>= 1) v += __shfl_xor(v, off);
    if (j == 0) out[b] = logC + __logf(v);
}

extern "C" void kernel_launch(void* const* d_in, const int* in_sizes, int n_in,
                              void* d_out, int out_size, void* d_ws, size_t ws_size,
                              hipStream_t stream) {
    const float* emissions = (const float*)d_in[0];
    const int*   mask      = (const int*)d_in[1];
    const float* trans     = (const float*)d_in[2];
    const float* start_t   = (const float*)d_in[3];
    const float* end_t     = (const float*)d_in[4];
    float* out = (float*)d_out;

    crf_fwd<<<BATCH, NL, 0, stream>>>(emissions, mask, trans, start_t, end_t, out);
}